// Round 11
// baseline (1060.705 us; speedup 1.0000x reference)
//
#include <hip/hip_runtime.h>
#include <cstdint>

#define NVEH  4096
#define NT    1024
#define INW   12
#define UNITS 20

typedef float f32x2 __attribute__((ext_vector_type(2)));

#define PIN(v)  asm volatile("" : "+v"(v))

// Packed dual-FMA (VOP3P, full-rate on gfx950): acc.lo += w.lo*s, acc.hi += w.hi*s
// s broadcast from LOW half of src1.
#define PKFMA_LO(acc, w, s2) \
    asm("v_pk_fma_f32 %0, %1, %2, %0 op_sel:[0,0,0] op_sel_hi:[1,0,1]" \
        : "+v"(acc) : "v"(w), "v"(s2))
// broadcast HIGH half of src1.
#define PKFMA_HI(acc, w, s2) \
    asm("v_pk_fma_f32 %0, %1, %2, %0 op_sel:[0,1,0] op_sel_hi:[1,1,1]" \
        : "+v"(acc) : "v"(w), "v"(s2))
// packed mul broadcasting low half of src1 (chain head)
#define PKMUL_LO(dst, w, s2) \
    asm("v_pk_mul_f32 %0, %1, %2 op_sel:[0,0] op_sel_hi:[1,0]" \
        : "=v"(dst) : "v"(w), "v"(s2))
// elementwise packed fma
#define PKFMA(acc, a, b) \
    asm("v_pk_fma_f32 %0, %1, %2, %0" : "+v"(acc) : "v"(a), "v"(b))

__device__ __forceinline__ float fexp2(float x) { return __builtin_amdgcn_exp2f(x); }
__device__ __forceinline__ float frcp(float x)  { return __builtin_amdgcn_rcpf(x); }

// async global -> LDS, 16B per active lane, dest = uniform base + lane*16
__device__ __forceinline__ void gload_lds16(const float* g, float* l) {
    __builtin_amdgcn_global_load_lds(
        (const __attribute__((address_space(1))) unsigned int*)g,
        (__attribute__((address_space(3))) unsigned int*)l,
        16, 0, 0);
}

// k=2 TIME-INTERLEAVED vehicle sets in ONE wave (P,Q: 3 vehicles each).
// Law from r3..r10: T_wave = issue + E, E~1180cy invariant, co-resident waves
// never shorten a wave's own wall. Fix: give the static scheduler a second
// INDEPENDENT instruction stream (separate code, shared weights) so each
// set's LDS/trans latency is filled by the other set's compute.
__global__ __attribute__((amdgpu_waves_per_eu(1, 1))) __launch_bounds__(64)
void rnncf_kernel(const float* __restrict__ x,          // (NVEH, NT, 12)
                  const float* __restrict__ init_state, // (NVEH, 2)
                  const float* __restrict__ hs,         // (2, NVEH, 20)
                  const float* __restrict__ K,          // (12, 80)
                  const float* __restrict__ R,          // (20, 80)
                  const float* __restrict__ bias,       // (80)
                  const float* __restrict__ W2,         // (20, 10)
                  const float* __restrict__ b2,         // (10)
                  const float* __restrict__ Wlc,        // (10, 3)
                  const float* __restrict__ blc,        // (3)
                  const float* __restrict__ W1,         // (10, 1)
                  const float* __restrict__ b1,         // (1)
                  float* __restrict__ out)
{
    const int lane = threadIdx.x;
    const int grp  = lane / 20;     // 0..2 = vehicle slot, 3 = idle lanes
    const int sub  = lane % 20;     // unit index / head index
    const int vehP = blockIdx.x * 6 + grp;
    const int vehQ = vehP + 3;
    const bool aP = (grp < 3) && (vehP < NVEH);
    const bool aQ = (grp < 3) && (vehQ < NVEH);
    const int vsP = (vehP < NVEH) ? vehP : NVEH - 1;
    const int vsQ = (vehQ < NVEH) ? vehQ : NVEH - 1;

    __shared__ __align__(16) float x_lds[8][6][12];   // depth-8 FIFO, 6 vehicles
    __shared__ __align__(16) float h_lds[2][4][20];   // per-set h banks
    __shared__ __align__(16) float x2_lds[2][4][12];  // per-set x2 banks
    __shared__ __align__(16) float wlcl[3][12];       // Wlc column rows (48B apart)

    // ---- shared folded weights (r4/r7-verified math), pk pairs ----
    const float L2E = 1.4426950408889634f;
    const float sI = -L2E, sF = -L2E, sG = 2.0f * L2E, sO = -L2E;
    f32x2 K01[12], K23[12], R01[20], R23[20], bz01, bz23, kd01, kd23;
#pragma unroll
    for (int k = 0; k < 12; ++k) {
        float ck = (k < 3) ? 0.01f : (k < 6) ? -0.01f : 0.025f;
        K01[k][0] = sI * ck * K[k * 80 + sub];
        K01[k][1] = sF * ck * K[k * 80 + 20 + sub];
        K23[k][0] = sG * ck * K[k * 80 + 40 + sub];
        K23[k][1] = sO * ck * K[k * 80 + 60 + sub];
    }
    {
        float aI = 0, aF = 0, aG = 0, aO = 0;
        for (int k = 0; k < 6; ++k) {
            float sgn = (k < 3) ? -0.01f : 0.01f;
            aI += sgn * K[k * 80 + sub];
            aF += sgn * K[k * 80 + 20 + sub];
            aG += sgn * K[k * 80 + 40 + sub];
            aO += sgn * K[k * 80 + 60 + sub];
        }
        kd01[0] = sI * aI; kd01[1] = sF * aF;
        kd23[0] = sG * aG; kd23[1] = sO * aO;
    }
    bz01[0] = sI * bias[sub];      bz01[1] = sF * bias[20 + sub];
    bz23[0] = sG * bias[40 + sub]; bz23[1] = sO * bias[60 + sub];
#pragma unroll
    for (int k = 0; k < 20; ++k) {
        R01[k][0] = sI * R[k * 80 + sub];      R01[k][1] = sF * R[k * 80 + 20 + sub];
        R23[k][0] = sG * R[k * 80 + 40 + sub]; R23[k][1] = sO * R[k * 80 + 60 + sub];
    }
    const int mh = (sub < 10) ? sub : 9;
    f32x2 W2p[10];
#pragma unroll
    for (int u = 0; u < 10; ++u) {
        W2p[u][0] = W2[(2 * u) * 10 + mh];
        W2p[u][1] = W2[(2 * u + 1) * 10 + mh];
    }
    float b2s = b2[mh];
    const int jl = (sub < 3) ? sub : 0;
    float blcs = blc[jl];
    PIN(bz01); PIN(bz23); PIN(kd01); PIN(kd23);
#pragma unroll
    for (int k = 0; k < 12; ++k) { PIN(K01[k]); PIN(K23[k]); }
#pragma unroll
    for (int k = 0; k < 20; ++k) { PIN(R01[k]); PIN(R23[k]); }
#pragma unroll
    for (int u = 0; u < 10; ++u) PIN(W2p[u]);
    PIN(b2s); PIN(blcs);

    // Wlc -> LDS row table (rows 48B apart: lanes 0..2 conflict-free)
    for (int idx = lane; idx < 36; idx += 64) {
        int j = idx / 12, m = idx % 12;
        wlcl[j][m] = (m < 10) ? Wlc[m * 3 + j] : 0.0f;
    }

    // ---- per-set state ----
    float posP = init_state[vsP * 2 + 0], spdP = init_state[vsP * 2 + 1];
    float posQ = init_state[vsQ * 2 + 0], spdQ = init_state[vsQ * 2 + 1];
    float cP = hs[(size_t)NVEH * UNITS + (size_t)vsP * UNITS + sub];
    float cQ = hs[(size_t)NVEH * UNITS + (size_t)vsQ * UNITS + sub];
    float hnewP = hs[(size_t)vsP * UNITS + sub];
    float hnewQ = hs[(size_t)vsQ * UNITS + sub];

    h_lds[0][grp][sub] = hnewP;
    h_lds[1][grp][sub] = hnewQ;
    __builtin_amdgcn_wave_barrier();
    f32x2 hrpP[10], hrpQ[10];
#pragma unroll
    for (int q = 0; q < 5; ++q) {
        float4 v = ((const float4*)&h_lds[0][grp][0])[q];
        hrpP[2*q][0]   = v.x; hrpP[2*q][1]   = v.y;
        hrpP[2*q+1][0] = v.z; hrpP[2*q+1][1] = v.w;
        float4 w = ((const float4*)&h_lds[1][grp][0])[q];
        hrpQ[2*q][0]   = w.x; hrpQ[2*q][1]   = w.y;
        hrpQ[2*q+1][0] = w.z; hrpQ[2*q+1][1] = w.w;
    }
    __builtin_amdgcn_wave_barrier();

    // ---- x FIFO: lanes 0..17 stage 16B/step for 6 vehicles ----
    const bool stg = (lane < 18);
    int sveh = blockIdx.x * 6 + lane / 3;
    if (sveh > NVEH - 1) sveh = NVEH - 1;
    const float* sgp = x + (size_t)sveh * NT * INW + (lane % 3) * 4;
    if (stg) {
#pragma unroll
        for (int t0 = 0; t0 < 8; ++t0)
            gload_lds16(sgp + (size_t)t0 * INW, &x_lds[t0][0][0]);
    }

    // K-dot from LDS slot for a given local vehicle row
#define KDOT(zk01, zk23, row, slot)                                          \
    {                                                                        \
        float4 u0 = ((const float4*)&x_lds[slot][row][0])[0];                \
        float4 u1 = ((const float4*)&x_lds[slot][row][0])[1];                \
        float4 u2 = ((const float4*)&x_lds[slot][row][0])[2];                \
        f32x2 xp[6];                                                         \
        xp[0][0]=u0.x; xp[0][1]=u0.y; xp[1][0]=u0.z; xp[1][1]=u0.w;          \
        xp[2][0]=u1.x; xp[2][1]=u1.y; xp[3][0]=u1.z; xp[3][1]=u1.w;          \
        xp[4][0]=u2.x; xp[4][1]=u2.y; xp[5][0]=u2.z; xp[5][1]=u2.w;          \
        zk01 = bz01; zk23 = bz23;                                            \
        _Pragma("unroll")                                                    \
        for (int q_ = 0; q_ < 6; ++q_) {                                     \
            PKFMA_LO(zk01, K01[2*q_],   xp[q_]);                             \
            PKFMA_LO(zk23, K23[2*q_],   xp[q_]);                             \
            PKFMA_HI(zk01, K01[2*q_+1], xp[q_]);                             \
            PKFMA_HI(zk23, K23[2*q_+1], xp[q_]);                             \
        }                                                                    \
    }

#define RDOTS(za01, za23, zb01, zb23, hrp)                                   \
    PKMUL_LO(za01, R01[0], hrp[0]);                                          \
    PKMUL_LO(za23, R23[0], hrp[0]);                                          \
    PKFMA_HI(za01, R01[1], hrp[0]);                                          \
    PKFMA_HI(za23, R23[1], hrp[0]);                                          \
    _Pragma("unroll")                                                        \
    for (int q_ = 1; q_ < 5; ++q_) {                                         \
        PKFMA_LO(za01, R01[2*q_],   hrp[q_]);                                \
        PKFMA_LO(za23, R23[2*q_],   hrp[q_]);                                \
        PKFMA_HI(za01, R01[2*q_+1], hrp[q_]);                                \
        PKFMA_HI(za23, R23[2*q_+1], hrp[q_]);                                \
    }                                                                        \
    PKMUL_LO(zb01, R01[10], hrp[5]);                                         \
    PKMUL_LO(zb23, R23[10], hrp[5]);                                         \
    PKFMA_HI(zb01, R01[11], hrp[5]);                                         \
    PKFMA_HI(zb23, R23[11], hrp[5]);                                         \
    _Pragma("unroll")                                                        \
    for (int q_ = 6; q_ < 10; ++q_) {                                        \
        PKFMA_LO(zb01, R01[2*q_],   hrp[q_]);                                \
        PKFMA_LO(zb23, R23[2*q_],   hrp[q_]);                                \
        PKFMA_HI(zb01, R01[2*q_+1], hrp[q_]);                                \
        PKFMA_HI(zb23, R23[2*q_+1], hrp[q_]);                                \
    }

    // ---- prologue: t=0 partials for both sets ----
    asm volatile("s_waitcnt vmcnt(7)" ::: "memory");   // slot 0 resident
    f32x2 zKx01P, zKx23P, zA01P, zA23P, zB01P, zB23P;
    f32x2 zKx01Q, zKx23Q, zA01Q, zA23Q, zB01Q, zB23Q;
    KDOT(zKx01P, zKx23P, grp, 0);
    KDOT(zKx01Q, zKx23Q, 3 + grp, 0);
    RDOTS(zA01P, zA23P, zB01P, zB23P, hrpP);
    RDOTS(zA01Q, zA23Q, zB01Q, zB23Q, hrpQ);

    f32x2 x2pP[5], x2pQ[5];
#pragma unroll
    for (int q = 0; q < 5; ++q) {
        x2pP[q][0] = 0.0f; x2pP[q][1] = 0.0f;
        x2pQ[q][0] = 0.0f; x2pQ[q][1] = 0.0f;
    }
    f32x2 pospP, pospQ; pospP[1] = 0.0f; pospQ[1] = 0.0f;

    float* trajpP = out + (size_t)vsP * NT;
    float* trajpQ = out + (size_t)vsQ * NT;
    float* lcpP   = out + (size_t)NVEH * NT + (size_t)vsP * NT * 3;
    float* lcpQ   = out + (size_t)NVEH * NT + (size_t)vsQ * NT * 3;

    // A+B+C+h-write for one set
#define STEP_ABC(t, pos, spd, c, hnew, x2p, posp, zKx01, zKx23,              \
                 zA01, zA23, zB01, zB23, act, lcp, trajp, bank)              \
    {                                                                        \
        if ((t) > 0) {                                                       \
            float a0 = b1[0], a1 = 0.0f;                                     \
            _Pragma("unroll")                                                \
            for (int m_ = 0; m_ < 5; ++m_) {                                 \
                a0 = fmaf(x2p[m_][0], W1[2*m_],   a0);                       \
                a1 = fmaf(x2p[m_][1], W1[2*m_+1], a1);                       \
            }                                                                \
            spd = fmaf(0.1f, fmaf(10.0f, a0 + a1, -6.0f), spd);              \
            if (act && sub < 3) {                                            \
                f32x2 lc2; lc2[0] = blcs; lc2[1] = 0.0f;                     \
                _Pragma("unroll")                                            \
                for (int m_ = 0; m_ < 5; ++m_) {                             \
                    f32x2 w_ = ((const f32x2*)&wlcl[jl][0])[m_];             \
                    PKFMA(lc2, x2p[m_], w_);                                 \
                }                                                            \
                lcp[((t) - 1) * 3 + sub] = lc2[0] + lc2[1];                  \
            }                                                                \
        }                                                                    \
        const float pold_ = pos;                                             \
        pos = fmaf(0.1f, spd, pold_);                                        \
        if (act && sub == 0) trajp[t] = pos;                                 \
        posp[0] = pold_;                                                     \
        f32x2 z01 = zKx01, z23 = zKx23;                                      \
        PKFMA_LO(z01, kd01, posp);                                           \
        PKFMA_LO(z23, kd23, posp);                                           \
        z01 = (z01 + zA01) + zB01;                                           \
        z23 = (z23 + zA23) + zB23;                                           \
        float ig = frcp(1.0f + fexp2(z01[0]));                               \
        float fg = frcp(1.0f + fexp2(z01[1]));                               \
        float gg = 1.0f - 2.0f * frcp(fexp2(z23[0]) + 1.0f);                 \
        float og = frcp(1.0f + fexp2(z23[1]));                               \
        c = fmaf(fg, c, ig * gg);                                            \
        float th = 1.0f - 2.0f * frcp(fexp2(2.8853900817779268f * c) + 1.0f);\
        hnew = og * th;                                                      \
        h_lds[bank][grp][sub] = hnew;                                        \
    }

    // h-read + G(K-dot t+1) + E(head+x2) + F(R-dots) for one set
#define STEP_DGEF(t, hrp, x2p, zKx01, zKx23, zA01, zA23, zB01, zB23,         \
                  bank, xrow)                                                \
    {                                                                        \
        _Pragma("unroll")                                                    \
        for (int q_ = 0; q_ < 5; ++q_) {                                     \
            float4 v_ = ((const float4*)&h_lds[bank][grp][0])[q_];           \
            hrp[2*q_][0]   = v_.x; hrp[2*q_][1]   = v_.y;                    \
            hrp[2*q_+1][0] = v_.z; hrp[2*q_+1][1] = v_.w;                    \
        }                                                                    \
        int tn_ = (t) + 1; if (tn_ > NT - 1) tn_ = NT - 1;                   \
        KDOT(zKx01, zKx23, xrow, tn_ & 7);                                   \
        f32x2 xm2; xm2[0] = b2s; xm2[1] = 0.0f;                              \
        _Pragma("unroll")                                                    \
        for (int u_ = 0; u_ < 10; ++u_) PKFMA(xm2, hrp[u_], W2p[u_]);        \
        float xm_ = fmaxf(xm2[0] + xm2[1], 0.0f);                            \
        if (sub < 10) x2_lds[bank][grp][sub] = xm_;                          \
        {                                                                    \
            float4 a_ = ((const float4*)&x2_lds[bank][grp][0])[0];           \
            float4 b_ = ((const float4*)&x2_lds[bank][grp][0])[1];           \
            float2 e_ = *((const float2*)&x2_lds[bank][grp][8]);             \
            x2p[0][0]=a_.x; x2p[0][1]=a_.y; x2p[1][0]=a_.z; x2p[1][1]=a_.w;  \
            x2p[2][0]=b_.x; x2p[2][1]=b_.y; x2p[3][0]=b_.z; x2p[3][1]=b_.w;  \
            x2p[4][0]=e_.x; x2p[4][1]=e_.y;                                  \
        }                                                                    \
        RDOTS(zA01, zA23, zB01, zB23, hrp);                                  \
    }

    for (int tb = 0; tb < NT; tb += 4) {
        // rotated body reads slots tb+1..tb+4; keep newest 3 loads in flight
        asm volatile("s_waitcnt vmcnt(3)" ::: "memory");

#pragma unroll
        for (int j = 0; j < 4; ++j) {
            const int t = tb + j;
            // P's h-write -> h-read gap is spanned by Q's ABC (~250cy);
            // Q's gap by P's DGEF (~400cy). Streams are independent: the
            // scheduler interleaves freely (macros are non-volatile asm).
            STEP_ABC(t, posP, spdP, cP, hnewP, x2pP, pospP, zKx01P, zKx23P,
                     zA01P, zA23P, zB01P, zB23P, aP, lcpP, trajpP, 0);
            STEP_ABC(t, posQ, spdQ, cQ, hnewQ, x2pQ, pospQ, zKx01Q, zKx23Q,
                     zA01Q, zA23Q, zB01Q, zB23Q, aQ, lcpQ, trajpQ, 1);
            STEP_DGEF(t, hrpP, x2pP, zKx01P, zKx23P,
                      zA01P, zA23P, zB01P, zB23P, 0, grp);
            STEP_DGEF(t, hrpQ, x2pQ, zKx01Q, zKx23Q,
                      zA01Q, zA23Q, zB01Q, zB23Q, 1, 3 + grp);
        }

        // issue loads for steps tb+8 .. tb+11 into the slots just consumed
        if (stg) {
#pragma unroll
            for (int j = 0; j < 4; ++j) {
                int tt = tb + 8 + j; if (tt > NT - 1) tt = NT - 1;
                gload_lds16(sgp + (size_t)tt * INW, &x_lds[(tb + j) & 7][0][0]);
            }
        }
    }

    // ---- epilogue: finish head for step NT-1, both sets ----
#define EPI(x2p, spd, act, lcp)                                              \
    {                                                                        \
        float a0 = b1[0], a1 = 0.0f;                                         \
        _Pragma("unroll")                                                    \
        for (int m_ = 0; m_ < 5; ++m_) {                                     \
            a0 = fmaf(x2p[m_][0], W1[2*m_],   a0);                           \
            a1 = fmaf(x2p[m_][1], W1[2*m_+1], a1);                           \
        }                                                                    \
        spd = fmaf(0.1f, fmaf(10.0f, a0 + a1, -6.0f), spd);                  \
        if (act && sub < 3) {                                                \
            f32x2 lc2; lc2[0] = blcs; lc2[1] = 0.0f;                         \
            _Pragma("unroll")                                                \
            for (int m_ = 0; m_ < 5; ++m_) {                                 \
                f32x2 w_ = ((const f32x2*)&wlcl[jl][0])[m_];                 \
                PKFMA(lc2, x2p[m_], w_);                                     \
            }                                                                \
            lcp[(NT - 1) * 3 + sub] = lc2[0] + lc2[1];                       \
        }                                                                    \
    }
    EPI(x2pP, spdP, aP, lcpP);
    EPI(x2pQ, spdQ, aQ, lcpQ);

    {
        float* spdf = out + (size_t)NVEH * NT * 4;
        float* hf   = spdf + NVEH;
        float* cf   = hf + (size_t)NVEH * UNITS;
        if (aP) {
            if (sub == 0) spdf[vehP] = spdP;
            hf[(size_t)vehP * UNITS + sub] = hnewP;
            cf[(size_t)vehP * UNITS + sub] = cP;
        }
        if (aQ) {
            if (sub == 0) spdf[vehQ] = spdQ;
            hf[(size_t)vehQ * UNITS + sub] = hnewQ;
            cf[(size_t)vehQ * UNITS + sub] = cQ;
        }
    }
}

extern "C" void kernel_launch(void* const* d_in, const int* in_sizes, int n_in,
                              void* d_out, int out_size, void* d_ws, size_t ws_size,
                              hipStream_t stream) {
    const float* x    = (const float*)d_in[0];
    const float* st0  = (const float*)d_in[1];
    const float* hs   = (const float*)d_in[2];
    const float* K    = (const float*)d_in[3];
    const float* R    = (const float*)d_in[4];
    const float* bias = (const float*)d_in[5];
    const float* W2   = (const float*)d_in[6];
    const float* b2   = (const float*)d_in[7];
    const float* Wlc  = (const float*)d_in[8];
    const float* blc  = (const float*)d_in[9];
    const float* W1   = (const float*)d_in[10];
    const float* b1   = (const float*)d_in[11];
    float* out = (float*)d_out;

    dim3 grid((NVEH + 5) / 6);   // 683 blocks: 2 interleaved 3-vehicle sets/wave
    dim3 block(64);
    hipLaunchKernelGGL(rnncf_kernel, grid, block, 0, stream,
                       x, st0, hs, K, R, bias, W2, b2, Wlc, blc, W1, b1, out);
}